// Round 4
// baseline (314.947 us; speedup 1.0000x reference)
//
#include <hip/hip_runtime.h>

#define NTHREADS 512

// Geometry (fixed by the reference)
#define NB   4
#define HH   256
#define WW   256

// u16-unit LDS offsets. Total 24832 u16 = 49,664 B -> 3 blocks/CU (148,992 <= 163,840)
// Region A [0..8191]:      XF (x B-frags) -> HID (all rounds) -> CORR
// Region B [8192..16383]:  Q -> RED (stage-4 partials) -> BFR
// Region C [16384..24575]: K
#define XF     0
#define HIDA   0        // single HID buffer, aliases XF (full barriers fence it)
#define Q_U    8192     // 8192 u16 f16 [c][(slot^cs)*8+j]  (dead after stage 3)
#define K_U    16384    // 8192 u16 f16                     (dead after stage 3)
#define CORRU  0        // 8192 u16 f16 (alias A; HID dead after rnd-5 dw + barrier)
#define REDU   8192     // 2048 u16 f32 partials (alias Q; Q dead after stage 3)
#define BFRU   8192     // 8192 u16 bf16 gated B-frags (alias Q/RED; RED dead after mu/rs)
#define MU_U   24576    // 128 u16 = 64 f32
#define RS_U   24704    // 128 u16 = 64 f32
#define SMEM_U 24832

typedef short s16x8 __attribute__((ext_vector_type(8)));
typedef float f32x16 __attribute__((ext_vector_type(16)));
typedef _Float16 h16x8 __attribute__((ext_vector_type(8)));
typedef _Float16 h16x4 __attribute__((ext_vector_type(4)));
typedef _Float16 h16x2 __attribute__((ext_vector_type(2)));

__device__ inline unsigned short f2bf(float f) {      // RNE f32 -> bf16
    unsigned u = __builtin_bit_cast(unsigned, f);
    u += 0x7FFFu + ((u >> 16) & 1u);
    return (unsigned short)(u >> 16);
}
__device__ inline float bf2f(unsigned short s) {
    return __builtin_bit_cast(float, (unsigned)s << 16);
}
__device__ inline unsigned short f2h(float f) {
    _Float16 h = (_Float16)f;
    return __builtin_bit_cast(unsigned short, h);
}

// v_dot2_f32_f16: d = a.lo*b.lo + a.hi*b.hi + c  (f16 mul, f32 accumulate)
__device__ inline float fdot2(unsigned a, unsigned b, float c) {
#if __has_builtin(__builtin_amdgcn_fdot2)
    return __builtin_amdgcn_fdot2(__builtin_bit_cast(h16x2, a),
                                  __builtin_bit_cast(h16x2, b), c, false);
#else
    h16x2 av = __builtin_bit_cast(h16x2, a);
    h16x2 bv = __builtin_bit_cast(h16x2, b);
    return c + (float)av[0] * (float)bv[0] + (float)av[1] * (float)bv[1];
#endif
}

// ---- prepack: w1 + wout(hi/lo) -> bf16 MFMA A-fragment order in d_ws ----
__global__ __launch_bounds__(256)
void fsas_prepack(const float* __restrict__ w1, const float* __restrict__ wout,
                  unsigned short* __restrict__ ws)
{
    int t = blockIdx.x * 256 + threadIdx.x;   // 0..40959
    if (t < 24576) {
        int b = t & 7, ln = (t >> 3) & 63, ks = (t >> 9) & 3, mtc = t >> 11;
        int l32 = ln & 31, half = ln >> 5;
        int o = mtc * 32 + l32;
        int kk = ks * 16 + half * 8 + b;
        ws[t] = f2bf(w1[o * 64 + kk]);
    } else if (t < 40960) {
        int idx = t - 24576;
        int lo = idx >= 8192;
        if (lo) idx -= 8192;
        int b = idx & 7, ln = (idx >> 3) & 63, ks = (idx >> 9) & 7, mtp = idx >> 12;
        int l32 = ln & 31, half = ln >> 5;
        int o = mtp * 32 + l32;
        int kk = ks * 16 + half * 8 + b;
        float v = wout[o * 128 + kk];
        unsigned short hi = f2bf(v);
        ws[t] = lo ? f2bf(v - bf2f(hi)) : hi;
    }
}

__global__ __launch_bounds__(NTHREADS, 4)
void fsas_fused(const float* __restrict__ x,
                const float* __restrict__ wdw,   // [384][3][3]
                const unsigned short* __restrict__ wsu,
                const float* __restrict__ lnw,
                const float* __restrict__ lnb,
                float* __restrict__ out)
{
    __shared__ unsigned short su[SMEM_U];

    const int tid = threadIdx.x;
    const int wv  = tid >> 6;      // 0..7
    const int ln  = tid & 63;
    const int l32 = ln & 31, half = ln >> 5;
    // XCD-aware swizzle: 4096 blocks, 8 XCDs round-robin on dispatch index.
    const int lin  = (blockIdx.z * 32 + blockIdx.y) * 32 + blockIdx.x;
    const int orig = (lin & 7) * 512 + (lin >> 3);
    const int pw = orig & 31;
    const int ph = (orig >> 5) & 31;
    const int b  = orig >> 10;
    const int h0  = ph * 8;
    const int w0  = pw * 8;

    // ---- 1) x tile (10x10 + halo) -> bf16 B-fragments; pad slots get 0 ----
    for (int idx = tid; idx < 8192; idx += NTHREADS) {
        int c = idx >> 7, pos = idx & 127;
        float v = 0.f;
        if (pos < 100) {
            int r = pos / 10, q = pos - r * 10;
            int h = h0 - 1 + r, w = w0 - 1 + q;
            if ((unsigned)h < (unsigned)HH && (unsigned)w < (unsigned)WW)
                v = x[((b * 64 + c) * HH + h) * WW + w];
        }
        int lane = (pos & 31) + 32 * ((c >> 3) & 1);
        int nt = pos >> 5, ks = c >> 4, bb = c & 7;
        su[XF + ((nt * 4 + ks) * 64 + lane) * 8 + bb] = f2bf(v);
    }
    __syncthreads();

    // ---- 2) six half-rounds: MFMA (64 out-ch) + depthwise 3x3 ----
    const s16x8* waf = (const s16x8*)wsu;
    const int mt2 = wv & 1, nt = (wv >> 1) & 3;
    const int pos = nt * 32 + l32;
    const int r10 = pos / 10, c10 = pos - r10 * 10;
    const int posoff = r10 * 12 + c10;
    const bool pvalid = pos < 100;

    // Hoist the (round-invariant) B-fragments into registers; XF LDS dies here.
    s16x8 breg[4];
#pragma unroll
    for (int ks = 0; ks < 4; ++ks)
        breg[ks] = *(const s16x8*)(su + XF + ((nt * 4 + ks) * 64 + ln) * 8);
    __syncthreads();   // all breg reads done before rnd-0 HID overwrites XF

    uint4 vA, vB;      // V channels (oc) and (64+oc), row py — kept in registers
    const int dw_oc = tid >> 3, dw_py = tid & 7;

#pragma unroll
    for (int rnd = 0; rnd < 6; ++rnd) {
        {
            int mtc = rnd * 2 + mt2;
            f32x16 acc = {};
#pragma unroll
            for (int ks = 0; ks < 4; ++ks) {
                s16x8 afr = waf[(mtc * 4 + ks) * 64 + ln];
                acc = __builtin_amdgcn_mfma_f32_32x32x16_bf16(afr, breg[ks], acc, 0, 0, 0);
            }
            if (pvalid) {
#pragma unroll
                for (int rr = 0; rr < 16; ++rr) {
                    int o_l = mt2 * 32 + (rr & 3) + 8 * (rr >> 2) + 4 * half;
                    su[HIDA + o_l * 120 + posoff] = f2h(acc[rr]);
                }
            }
        }
        __syncthreads();
        {
            int oc = dw_oc, py = dw_py;
            const float* wr = wdw + (rnd * 64 + oc) * 9;
            float wgt[9];
#pragma unroll
            for (int t = 0; t < 9; ++t) wgt[t] = wr[t];
            const unsigned short* hb = su + HIDA + oc * 120 + py * 12;
            _Float16 hh[3][12];
#pragma unroll
            for (int rr = 0; rr < 3; ++rr) {
                uint2 ua = *(const uint2*)(hb + rr * 12);
                uint2 ub = *(const uint2*)(hb + rr * 12 + 4);
                uint2 uc = *(const uint2*)(hb + rr * 12 + 8);
                h16x4 a = __builtin_bit_cast(h16x4, ua);
                h16x4 bq = __builtin_bit_cast(h16x4, ub);
                h16x4 cq = __builtin_bit_cast(h16x4, uc);
#pragma unroll
                for (int t = 0; t < 4; ++t) { hh[rr][t] = a[t]; hh[rr][4 + t] = bq[t]; hh[rr][8 + t] = cq[t]; }
            }
            float o_[8];
#pragma unroll
            for (int px = 0; px < 8; ++px) {
                o_[px] = wgt[0] * (float)hh[0][px] + wgt[1] * (float)hh[0][px + 1] + wgt[2] * (float)hh[0][px + 2]
                       + wgt[3] * (float)hh[1][px] + wgt[4] * (float)hh[1][px + 1] + wgt[5] * (float)hh[1][px + 2]
                       + wgt[6] * (float)hh[2][px] + wgt[7] * (float)hh[2][px + 1] + wgt[8] * (float)hh[2][px + 2];
            }
            uint4 o4;
            o4.x = (unsigned)f2h(o_[0]) | ((unsigned)f2h(o_[1]) << 16);
            o4.y = (unsigned)f2h(o_[2]) | ((unsigned)f2h(o_[3]) << 16);
            o4.z = (unsigned)f2h(o_[4]) | ((unsigned)f2h(o_[5]) << 16);
            o4.w = (unsigned)f2h(o_[6]) | ((unsigned)f2h(o_[7]) << 16);
            if (rnd < 4) {
                // q (rnds 0-1) and k (rnds 2-3) -> LDS (regions B and C)
                int buf = rnd >> 1;
                int cb  = (rnd & 1) * 64 + oc;
                int cs  = cb & 7;
                *(uint4*)(su + Q_U + buf * 8192 + cb * 64 + ((py ^ cs) * 8)) = o4;
            } else if (rnd == 4) {
                vA = o4;                     // v channel oc
            } else {
                vB = o4;                     // v channel 64+oc
            }
        }
        // WAR fence: next round's MFMA overwrites HID that this dw just read.
        // rnd5's fence is the post-loop barrier (CORR overwrites region A).
        if (rnd < 5) __syncthreads();
    }
    __syncthreads();

    // ---- 3) 8x8 circular conv via v_dot2_f32_f16; thread (oc,py): row py of
    //         channels oc and 64+oc. q-row reads broadcast across 8 lanes. ----
    {
        int oc = dw_oc, py = dw_py;
#pragma unroll
        for (int cc = 0; cc < 2; ++cc) {
            int c = oc + cc * 64, cs = c & 7;
            const unsigned short* qr = su + Q_U + c * 64;
            const unsigned short* kr = su + K_U + c * 64;
            float o0[8] = {0.f,0.f,0.f,0.f,0.f,0.f,0.f,0.f};
#pragma unroll
            for (int a = 0; a < 8; ++a) {
                uint4 uq = *(const uint4*)(qr + ((a ^ cs) * 8));
                int k0 = (py - a) & 7;
                uint4 uk = *(const uint4*)(kr + ((k0 ^ cs) * 8));
                unsigned qw[4] = {uq.x, uq.y, uq.z, uq.w};
                unsigned kw[4] = {uk.x, uk.y, uk.z, uk.w};
                unsigned kr0[8];
#pragma unroll
                for (int p = 0; p < 4; ++p) {
                    kr0[2 * p]     = __builtin_amdgcn_perm(kw[(p + 3) & 3], kw[p], 0x07060100u);
                    kr0[2 * p + 1] = __builtin_amdgcn_alignbit(kw[p], kw[p], 16);
                }
#pragma unroll
                for (int j = 0; j < 8; ++j) {
#pragma unroll
                    for (int p = 0; p < 4; ++p)
                        o0[j] = fdot2(qw[p], kr0[(j - 2 * p) & 7], o0[j]);
                }
            }
            uint4 a4;
            a4.x = (unsigned)f2h(o0[0]) | ((unsigned)f2h(o0[1]) << 16);
            a4.y = (unsigned)f2h(o0[2]) | ((unsigned)f2h(o0[3]) << 16);
            a4.z = (unsigned)f2h(o0[4]) | ((unsigned)f2h(o0[5]) << 16);
            a4.w = (unsigned)f2h(o0[6]) | ((unsigned)f2h(o0[7]) << 16);
            *(uint4*)(su + CORRU + c * 64 + ((py ^ cs) * 8)) = a4;
        }
    }
    __syncthreads();

    // ---- 4) LayerNorm stats: 8 partial groups x 64 px (RED aliases dead Q) ----
    {
        float* redF = (float*)(su + REDU);
        int px = tid & 63, grp = tid >> 6;     // grp 0..7
        int prow = px >> 3, pcol = px & 7;
        float s = 0.f, s2 = 0.f;
#pragma unroll
        for (int i = 0; i < 16; ++i) {
            int c = i * 8 + grp;
            float v = (float)__builtin_bit_cast(_Float16,
                        su[CORRU + c * 64 + ((prow ^ (c & 7)) * 8) + pcol]);
            s += v; s2 += v * v;
        }
        redF[grp * 64 + px] = s;
        redF[512 + grp * 64 + px] = s2;
    }
    __syncthreads();
    if (tid < 64) {
        float* redF = (float*)(su + REDU);
        float s = 0.f, s2 = 0.f;
#pragma unroll
        for (int g = 0; g < 8; ++g) {
            s  += redF[g * 64 + tid];
            s2 += redF[512 + g * 64 + tid];
        }
        float m = s * (1.f / 128.f);
        float var = s2 * (1.f / 128.f) - m * m;
        ((float*)(su + MU_U))[tid] = m;
        ((float*)(su + RS_U))[tid] = rsqrtf(var + 1e-5f);
    }
    __syncthreads();

    // ---- 5) normalize + affine + gate(V regs) -> bf16 B-frags (BFR aliases Q/RED) ----
    {
        int oc = dw_oc, py = dw_py;
        const float* muF = (const float*)(su + MU_U);
        const float* rsF = (const float*)(su + RS_U);
        float4 m0 = *(const float4*)(muF + py * 8);
        float4 m1 = *(const float4*)(muF + py * 8 + 4);
        float4 r0 = *(const float4*)(rsF + py * 8);
        float4 r1 = *(const float4*)(rsF + py * 8 + 4);
        float mm[8] = {m0.x, m0.y, m0.z, m0.w, m1.x, m1.y, m1.z, m1.w};
        float rr[8] = {r0.x, r0.y, r0.z, r0.w, r1.x, r1.y, r1.z, r1.w};
#pragma unroll
        for (int cc = 0; cc < 2; ++cc) {
            int c = oc + cc * 64, cs = c & 7;
            uint4 cu = *(const uint4*)(su + CORRU + c * 64 + ((py ^ cs) * 8));
            h16x8 ch = __builtin_bit_cast(h16x8, cu);
            h16x8 vh = __builtin_bit_cast(h16x8, cc ? vB : vA);
            float wc = lnw[c], bc = lnb[c];
            int base = BFRU + (((py >> 2) * 8 + (c >> 4)) * 64 + 8 * (py & 3) + 32 * ((c >> 3) & 1)) * 8 + (c & 7);
#pragma unroll
            for (int j = 0; j < 8; ++j) {
                float t = (((float)ch[j] - mm[j]) * rr[j] * wc + bc) * (float)vh[j];
                su[base + j * 8] = f2bf(t);
            }
        }
    }
    __syncthreads();

    // ---- 6) projection 128 -> 64: 4 waves, full-K (16 MFMAs as two 8-chains),
    //         direct f32 global store (no partial buffer, no stage 7) ----
    if (wv < 4) {
        int mtp = wv & 1, ntp = wv >> 1;
        const s16x8* whi = (const s16x8*)(wsu + 24576);
        const s16x8* wlo = (const s16x8*)(wsu + 32768);
        f32x16 acc_h = {}, acc_l = {};
#pragma unroll
        for (int ks = 0; ks < 8; ++ks) {
            s16x8 ah  = whi[(mtp * 8 + ks) * 64 + ln];
            s16x8 al  = wlo[(mtp * 8 + ks) * 64 + ln];
            s16x8 bfr = *(const s16x8*)(su + BFRU + ((ntp * 8 + ks) * 64 + ln) * 8);
            acc_h = __builtin_amdgcn_mfma_f32_32x32x16_bf16(ah, bfr, acc_h, 0, 0, 0);
            acc_l = __builtin_amdgcn_mfma_f32_32x32x16_bf16(al, bfr, acc_l, 0, 0, 0);
        }
        int px = ntp * 32 + l32;
        int py = px >> 3, wx = px & 7;
#pragma unroll
        for (int r = 0; r < 16; ++r) {
            int row = (r >> 2) * 8 + half * 4 + (r & 3);
            int o = mtp * 32 + row;
            out[(((size_t)(b * 64 + o) * HH) + h0 + py) * WW + w0 + wx] = acc_h[r] + acc_l[r];
        }
    }
}

extern "C" void kernel_launch(void* const* d_in, const int* in_sizes, int n_in,
                              void* d_out, int out_size, void* d_ws, size_t ws_size,
                              hipStream_t stream) {
    const float* x    = (const float*)d_in[0];
    const float* w1   = (const float*)d_in[1];
    const float* wdw  = (const float*)d_in[2];
    const float* wout = (const float*)d_in[3];
    const float* lnw  = (const float*)d_in[4];
    const float* lnb  = (const float*)d_in[5];
    float* o = (float*)d_out;
    unsigned short* ws = (unsigned short*)d_ws;

    fsas_prepack<<<160, 256, 0, stream>>>(w1, wout, ws);
    dim3 grid(32, 32, NB);
    fsas_fused<<<grid, dim3(NTHREADS), 0, stream>>>(x, wdw, ws, lnw, lnb, o);
}

// Round 5
// 311.147 us; speedup vs baseline: 1.0122x; 1.0122x over previous
//
#include <hip/hip_runtime.h>

#define NTHREADS 512

// Geometry (fixed by the reference)
#define NB   4
#define HH   256
#define WW   256

// u16-unit LDS offsets. Total 24832 u16 = 49,664 B -> 3 blocks/CU (148,992 <= 163,840)
// Region A [0..8191]:      XF (x B-frags) -> HID (all rounds) -> CORR
// Region B [8192..16383]:  Q -> RED (stage-4 partials) -> BFR
// Region C [16384..24575]: K
#define XF     0
#define HIDA   0        // single HID buffer, aliases XF (full barriers fence it)
#define Q_U    8192     // 8192 u16 f16 [c][(slot^cs)*8+j]  (dead after stage 3)
#define K_U    16384    // 8192 u16 f16                     (dead after stage 3)
#define CORRU  0        // 8192 u16 f16 (alias A; HID dead after rnd-5 dw + barrier)
#define REDU   8192     // 2048 u16 f32 partials (alias Q; Q dead after stage 3)
#define BFRU   8192     // 8192 u16 bf16 gated B-frags (alias Q/RED; RED dead after mu/rs)
#define MU_U   24576    // 128 u16 = 64 f32
#define RS_U   24704    // 128 u16 = 64 f32
#define SMEM_U 24832

typedef short s16x8 __attribute__((ext_vector_type(8)));
typedef float f32x16 __attribute__((ext_vector_type(16)));
typedef _Float16 h16x8 __attribute__((ext_vector_type(8)));
typedef _Float16 h16x4 __attribute__((ext_vector_type(4)));
typedef _Float16 h16x2 __attribute__((ext_vector_type(2)));

__device__ inline unsigned short f2bf(float f) {      // RNE f32 -> bf16
    unsigned u = __builtin_bit_cast(unsigned, f);
    u += 0x7FFFu + ((u >> 16) & 1u);
    return (unsigned short)(u >> 16);
}
__device__ inline float bf2f(unsigned short s) {
    return __builtin_bit_cast(float, (unsigned)s << 16);
}
__device__ inline unsigned short f2h(float f) {
    _Float16 h = (_Float16)f;
    return __builtin_bit_cast(unsigned short, h);
}

// v_dot2_f32_f16: d = a.lo*b.lo + a.hi*b.hi + c  (f16 mul, f32 accumulate)
__device__ inline float fdot2(unsigned a, unsigned b, float c) {
#if __has_builtin(__builtin_amdgcn_fdot2)
    return __builtin_amdgcn_fdot2(__builtin_bit_cast(h16x2, a),
                                  __builtin_bit_cast(h16x2, b), c, false);
#else
    h16x2 av = __builtin_bit_cast(h16x2, a);
    h16x2 bv = __builtin_bit_cast(h16x2, b);
    return c + (float)av[0] * (float)bv[0] + (float)av[1] * (float)bv[1];
#endif
}

// ---- prepack: w1 + wout(hi/lo) -> bf16 MFMA A-fragment order in d_ws ----
__global__ __launch_bounds__(256)
void fsas_prepack(const float* __restrict__ w1, const float* __restrict__ wout,
                  unsigned short* __restrict__ ws)
{
    int t = blockIdx.x * 256 + threadIdx.x;   // 0..40959
    if (t < 24576) {
        int b = t & 7, ln = (t >> 3) & 63, ks = (t >> 9) & 3, mtc = t >> 11;
        int l32 = ln & 31, half = ln >> 5;
        int o = mtc * 32 + l32;
        int kk = ks * 16 + half * 8 + b;
        ws[t] = f2bf(w1[o * 64 + kk]);
    } else if (t < 40960) {
        int idx = t - 24576;
        int lo = idx >= 8192;
        if (lo) idx -= 8192;
        int b = idx & 7, ln = (idx >> 3) & 63, ks = (idx >> 9) & 7, mtp = idx >> 12;
        int l32 = ln & 31, half = ln >> 5;
        int o = mtp * 32 + l32;
        int kk = ks * 16 + half * 8 + b;
        float v = wout[o * 128 + kk];
        unsigned short hi = f2bf(v);
        ws[t] = lo ? f2bf(v - bf2f(hi)) : hi;
    }
}

__global__ __launch_bounds__(NTHREADS, 4)
void fsas_fused(const float* __restrict__ x,
                const float* __restrict__ wdw,   // [384][3][3]
                const unsigned short* __restrict__ wsu,
                const float* __restrict__ lnw,
                const float* __restrict__ lnb,
                float* __restrict__ out)
{
    __shared__ unsigned short su[SMEM_U];

    const int tid = threadIdx.x;
    const int wv  = tid >> 6;      // 0..7
    const int ln  = tid & 63;
    const int l32 = ln & 31, half = ln >> 5;
    // XCD-aware swizzle: 4096 blocks, 8 XCDs round-robin on dispatch index.
    const int lin  = (blockIdx.z * 32 + blockIdx.y) * 32 + blockIdx.x;
    const int orig = (lin & 7) * 512 + (lin >> 3);
    const int pw = orig & 31;
    const int ph = (orig >> 5) & 31;
    const int b  = orig >> 10;
    const int h0  = ph * 8;
    const int w0  = pw * 8;

    // ---- 1) x tile (10x10 + halo) -> bf16 B-fragments; pad slots get 0 ----
    for (int idx = tid; idx < 8192; idx += NTHREADS) {
        int c = idx >> 7, pos = idx & 127;
        float v = 0.f;
        if (pos < 100) {
            int r = pos / 10, q = pos - r * 10;
            int h = h0 - 1 + r, w = w0 - 1 + q;
            if ((unsigned)h < (unsigned)HH && (unsigned)w < (unsigned)WW)
                v = x[((b * 64 + c) * HH + h) * WW + w];
        }
        int lane = (pos & 31) + 32 * ((c >> 3) & 1);
        int nt = pos >> 5, ks = c >> 4, bb = c & 7;
        su[XF + ((nt * 4 + ks) * 64 + lane) * 8 + bb] = f2bf(v);
    }
    __syncthreads();

    // ---- 2) six half-rounds: MFMA (64 out-ch) + depthwise 3x3 ----
    const s16x8* waf = (const s16x8*)wsu;
    const int mt2 = wv & 1, nt = (wv >> 1) & 3;
    const int pos = nt * 32 + l32;
    const int r10 = pos / 10, c10 = pos - r10 * 10;
    const int posoff = r10 * 12 + c10;
    const bool pvalid = pos < 100;

    // Hoist the (round-invariant) B-fragments into registers; XF LDS dies here.
    s16x8 breg[4];
#pragma unroll
    for (int ks = 0; ks < 4; ++ks)
        breg[ks] = *(const s16x8*)(su + XF + ((nt * 4 + ks) * 64 + ln) * 8);
    __syncthreads();   // all breg reads done before rnd-0 HID overwrites XF

    uint4 vA, vB;      // V channels (oc) and (64+oc), row py — kept in registers
    const int dw_oc = tid >> 3, dw_py = tid & 7;

#pragma unroll
    for (int rnd = 0; rnd < 6; ++rnd) {
        {
            int mtc = rnd * 2 + mt2;
            f32x16 acc = {};
#pragma unroll
            for (int ks = 0; ks < 4; ++ks) {
                s16x8 afr = waf[(mtc * 4 + ks) * 64 + ln];
                acc = __builtin_amdgcn_mfma_f32_32x32x16_bf16(afr, breg[ks], acc, 0, 0, 0);
            }
            if (pvalid) {
#pragma unroll
                for (int rr = 0; rr < 16; ++rr) {
                    int o_l = mt2 * 32 + (rr & 3) + 8 * (rr >> 2) + 4 * half;
                    su[HIDA + o_l * 120 + posoff] = f2h(acc[rr]);
                }
            }
        }
        __syncthreads();
        {
            int oc = dw_oc, py = dw_py;
            const float* wr = wdw + (rnd * 64 + oc) * 9;
            float wgt[9];
#pragma unroll
            for (int t = 0; t < 9; ++t) wgt[t] = wr[t];
            const unsigned short* hb = su + HIDA + oc * 120 + py * 12;
            _Float16 hh[3][12];
#pragma unroll
            for (int rr = 0; rr < 3; ++rr) {
                uint2 ua = *(const uint2*)(hb + rr * 12);
                uint2 ub = *(const uint2*)(hb + rr * 12 + 4);
                uint2 uc = *(const uint2*)(hb + rr * 12 + 8);
                h16x4 a = __builtin_bit_cast(h16x4, ua);
                h16x4 bq = __builtin_bit_cast(h16x4, ub);
                h16x4 cq = __builtin_bit_cast(h16x4, uc);
#pragma unroll
                for (int t = 0; t < 4; ++t) { hh[rr][t] = a[t]; hh[rr][4 + t] = bq[t]; hh[rr][8 + t] = cq[t]; }
            }
            float o_[8];
#pragma unroll
            for (int px = 0; px < 8; ++px) {
                o_[px] = wgt[0] * (float)hh[0][px] + wgt[1] * (float)hh[0][px + 1] + wgt[2] * (float)hh[0][px + 2]
                       + wgt[3] * (float)hh[1][px] + wgt[4] * (float)hh[1][px + 1] + wgt[5] * (float)hh[1][px + 2]
                       + wgt[6] * (float)hh[2][px] + wgt[7] * (float)hh[2][px + 1] + wgt[8] * (float)hh[2][px + 2];
            }
            uint4 o4;
            o4.x = (unsigned)f2h(o_[0]) | ((unsigned)f2h(o_[1]) << 16);
            o4.y = (unsigned)f2h(o_[2]) | ((unsigned)f2h(o_[3]) << 16);
            o4.z = (unsigned)f2h(o_[4]) | ((unsigned)f2h(o_[5]) << 16);
            o4.w = (unsigned)f2h(o_[6]) | ((unsigned)f2h(o_[7]) << 16);
            if (rnd < 4) {
                // q (rnds 0-1) and k (rnds 2-3) -> LDS (regions B and C)
                int buf = rnd >> 1;
                int cb  = (rnd & 1) * 64 + oc;
                int cs  = cb & 7;
                *(uint4*)(su + Q_U + buf * 8192 + cb * 64 + ((py ^ cs) * 8)) = o4;
            } else if (rnd == 4) {
                vA = o4;                     // v channel oc
            } else {
                vB = o4;                     // v channel 64+oc
            }
        }
        // WAR fence: next round's MFMA overwrites HID that this dw just read.
        // rnd5's fence is the post-loop barrier (CORR overwrites region A).
        if (rnd < 5) __syncthreads();
    }
    __syncthreads();

    // ---- 3) 8x8 circular conv via v_dot2_f32_f16; thread (oc,py): row py of
    //         channels oc and 64+oc. q-row reads broadcast across 8 lanes. ----
    {
        int oc = dw_oc, py = dw_py;
#pragma unroll
        for (int cc = 0; cc < 2; ++cc) {
            int c = oc + cc * 64, cs = c & 7;
            const unsigned short* qr = su + Q_U + c * 64;
            const unsigned short* kr = su + K_U + c * 64;
            float o0[8] = {0.f,0.f,0.f,0.f,0.f,0.f,0.f,0.f};
#pragma unroll
            for (int a = 0; a < 8; ++a) {
                uint4 uq = *(const uint4*)(qr + ((a ^ cs) * 8));
                int k0 = (py - a) & 7;
                uint4 uk = *(const uint4*)(kr + ((k0 ^ cs) * 8));
                unsigned qw[4] = {uq.x, uq.y, uq.z, uq.w};
                unsigned kw[4] = {uk.x, uk.y, uk.z, uk.w};
                unsigned kr0[8];
#pragma unroll
                for (int p = 0; p < 4; ++p) {
                    kr0[2 * p]     = __builtin_amdgcn_perm(kw[(p + 3) & 3], kw[p], 0x07060100u);
                    kr0[2 * p + 1] = __builtin_amdgcn_alignbit(kw[p], kw[p], 16);
                }
#pragma unroll
                for (int j = 0; j < 8; ++j) {
#pragma unroll
                    for (int p = 0; p < 4; ++p)
                        o0[j] = fdot2(qw[p], kr0[(j - 2 * p) & 7], o0[j]);
                }
            }
            uint4 a4;
            a4.x = (unsigned)f2h(o0[0]) | ((unsigned)f2h(o0[1]) << 16);
            a4.y = (unsigned)f2h(o0[2]) | ((unsigned)f2h(o0[3]) << 16);
            a4.z = (unsigned)f2h(o0[4]) | ((unsigned)f2h(o0[5]) << 16);
            a4.w = (unsigned)f2h(o0[6]) | ((unsigned)f2h(o0[7]) << 16);
            *(uint4*)(su + CORRU + c * 64 + ((py ^ cs) * 8)) = a4;
        }
    }
    __syncthreads();

    // ---- 4) LayerNorm stats: 8 partial groups x 64 px (RED aliases dead Q) ----
    {
        float* redF = (float*)(su + REDU);
        int px = tid & 63, grp = tid >> 6;     // grp 0..7
        int prow = px >> 3, pcol = px & 7;
        float s = 0.f, s2 = 0.f;
#pragma unroll
        for (int i = 0; i < 16; ++i) {
            int c = i * 8 + grp;
            float v = (float)__builtin_bit_cast(_Float16,
                        su[CORRU + c * 64 + ((prow ^ (c & 7)) * 8) + pcol]);
            s += v; s2 += v * v;
        }
        redF[grp * 64 + px] = s;
        redF[512 + grp * 64 + px] = s2;
    }
    __syncthreads();
    if (tid < 64) {
        float* redF = (float*)(su + REDU);
        float s = 0.f, s2 = 0.f;
#pragma unroll
        for (int g = 0; g < 8; ++g) {
            s  += redF[g * 64 + tid];
            s2 += redF[512 + g * 64 + tid];
        }
        float m = s * (1.f / 128.f);
        float var = s2 * (1.f / 128.f) - m * m;
        ((float*)(su + MU_U))[tid] = m;
        ((float*)(su + RS_U))[tid] = rsqrtf(var + 1e-5f);
    }
    __syncthreads();

    // ---- 5) normalize + affine + gate(V regs) -> bf16 B-frags (BFR aliases Q/RED) ----
    {
        int oc = dw_oc, py = dw_py;
        const float* muF = (const float*)(su + MU_U);
        const float* rsF = (const float*)(su + RS_U);
        float4 m0 = *(const float4*)(muF + py * 8);
        float4 m1 = *(const float4*)(muF + py * 8 + 4);
        float4 r0 = *(const float4*)(rsF + py * 8);
        float4 r1 = *(const float4*)(rsF + py * 8 + 4);
        float mm[8] = {m0.x, m0.y, m0.z, m0.w, m1.x, m1.y, m1.z, m1.w};
        float rr[8] = {r0.x, r0.y, r0.z, r0.w, r1.x, r1.y, r1.z, r1.w};
#pragma unroll
        for (int cc = 0; cc < 2; ++cc) {
            int c = oc + cc * 64, cs = c & 7;
            uint4 cu = *(const uint4*)(su + CORRU + c * 64 + ((py ^ cs) * 8));
            h16x8 ch = __builtin_bit_cast(h16x8, cu);
            h16x8 vh = __builtin_bit_cast(h16x8, cc ? vB : vA);
            float wc = lnw[c], bc = lnb[c];
            int base = BFRU + (((py >> 2) * 8 + (c >> 4)) * 64 + 8 * (py & 3) + 32 * ((c >> 3) & 1)) * 8 + (c & 7);
#pragma unroll
            for (int j = 0; j < 8; ++j) {
                float t = (((float)ch[j] - mm[j]) * rr[j] * wc + bc) * (float)vh[j];
                su[base + j * 8] = f2bf(t);
            }
        }
    }
    __syncthreads();

    // ---- 6) projection 128 -> 64: 4 waves, full-K, SINGLE accumulator
    //         (hi and lo chained into one f32x16 -> 16 fewer acc regs;
    //          (Ahi+Alo)·B identical up to f32 add order), direct store ----
    if (wv < 4) {
        int mtp = wv & 1, ntp = wv >> 1;
        const s16x8* whi = (const s16x8*)(wsu + 24576);
        const s16x8* wlo = (const s16x8*)(wsu + 32768);
        f32x16 acc = {};
#pragma unroll
        for (int ks = 0; ks < 8; ++ks) {
            s16x8 bfr = *(const s16x8*)(su + BFRU + ((ntp * 8 + ks) * 64 + ln) * 8);
            s16x8 ah  = whi[(mtp * 8 + ks) * 64 + ln];
            acc = __builtin_amdgcn_mfma_f32_32x32x16_bf16(ah, bfr, acc, 0, 0, 0);
            s16x8 al  = wlo[(mtp * 8 + ks) * 64 + ln];
            acc = __builtin_amdgcn_mfma_f32_32x32x16_bf16(al, bfr, acc, 0, 0, 0);
        }
        int px = ntp * 32 + l32;
        int py = px >> 3, wx = px & 7;
#pragma unroll
        for (int r = 0; r < 16; ++r) {
            int row = (r >> 2) * 8 + half * 4 + (r & 3);
            int o = mtp * 32 + row;
            out[(((size_t)(b * 64 + o) * HH) + h0 + py) * WW + w0 + wx] = acc[r];
        }
    }
}

extern "C" void kernel_launch(void* const* d_in, const int* in_sizes, int n_in,
                              void* d_out, int out_size, void* d_ws, size_t ws_size,
                              hipStream_t stream) {
    const float* x    = (const float*)d_in[0];
    const float* w1   = (const float*)d_in[1];
    const float* wdw  = (const float*)d_in[2];
    const float* wout = (const float*)d_in[3];
    const float* lnw  = (const float*)d_in[4];
    const float* lnb  = (const float*)d_in[5];
    float* o = (float*)d_out;
    unsigned short* ws = (unsigned short*)d_ws;

    fsas_prepack<<<160, 256, 0, stream>>>(w1, wout, ws);
    dim3 grid(32, 32, NB);
    fsas_fused<<<grid, dim3(NTHREADS), 0, stream>>>(x, wdw, ws, lnw, lnb, o);
}

// Round 6
// 276.331 us; speedup vs baseline: 1.1397x; 1.1260x over previous
//
#include <hip/hip_runtime.h>

#define NTHREADS 512

// Geometry (fixed by the reference)
#define NB   4
#define HH   256
#define WW   256

// u16-unit LDS offsets. Total 26880 u16 = 53,760 B -> 2 blocks/CU.
// Region A [0..8191]:      XF (x B-frags) -> HID (all rounds) -> CORR
// Region B [8192..17407]:  Q (stride-72 skewed) -> RED -> BFR
// Region C [17408..26623]: K (stride-72 skewed)
// MU/RS    [26624..26879]
#define XF     0
#define HIDA   0        // single HID buffer, aliases XF (full barriers fence it)
#define Q_U    8192     // 128ch x 72 u16 skewed rows      (dead after stage 3)
#define K_U    17408    // 128ch x 72 u16 skewed rows      (dead after stage 3)
#define CST    72       // channel stride (u16) for Q/K: 144B rotates bank map by 4/ch
#define CORRU  0        // 8192 u16 f16 (alias A; HID dead after rnd-5 dw + barrier)
#define REDU   8192     // 4096 u16 f32 partials (alias Q; Q dead after stage 3)
#define BFRU   8192     // 8192 u16 bf16 gated B-frags (alias Q/RED; RED dead after mu/rs)
#define MU_U   26624    // 128 u16 = 64 f32
#define RS_U   26752    // 128 u16 = 64 f32
#define SMEM_U 26880

typedef short s16x8 __attribute__((ext_vector_type(8)));
typedef float f32x16 __attribute__((ext_vector_type(16)));
typedef _Float16 h16x8 __attribute__((ext_vector_type(8)));
typedef _Float16 h16x4 __attribute__((ext_vector_type(4)));
typedef _Float16 h16x2 __attribute__((ext_vector_type(2)));

__device__ inline unsigned short f2bf(float f) {      // RNE f32 -> bf16
    unsigned u = __builtin_bit_cast(unsigned, f);
    u += 0x7FFFu + ((u >> 16) & 1u);
    return (unsigned short)(u >> 16);
}
__device__ inline float bf2f(unsigned short s) {
    return __builtin_bit_cast(float, (unsigned)s << 16);
}
__device__ inline unsigned short f2h(float f) {
    _Float16 h = (_Float16)f;
    return __builtin_bit_cast(unsigned short, h);
}

// v_dot2_f32_f16: d = a.lo*b.lo + a.hi*b.hi + c  (f16 mul, f32 accumulate)
__device__ inline float fdot2(unsigned a, unsigned b, float c) {
#if __has_builtin(__builtin_amdgcn_fdot2)
    return __builtin_amdgcn_fdot2(__builtin_bit_cast(h16x2, a),
                                  __builtin_bit_cast(h16x2, b), c, false);
#else
    h16x2 av = __builtin_bit_cast(h16x2, a);
    h16x2 bv = __builtin_bit_cast(h16x2, b);
    return c + (float)av[0] * (float)bv[0] + (float)av[1] * (float)bv[1];
#endif
}

// ---- prepack: w1 + wout(hi/lo) -> bf16 MFMA A-fragment order in d_ws ----
__global__ __launch_bounds__(256)
void fsas_prepack(const float* __restrict__ w1, const float* __restrict__ wout,
                  unsigned short* __restrict__ ws)
{
    int t = blockIdx.x * 256 + threadIdx.x;   // 0..40959
    if (t < 24576) {
        int b = t & 7, ln = (t >> 3) & 63, ks = (t >> 9) & 3, mtc = t >> 11;
        int l32 = ln & 31, half = ln >> 5;
        int o = mtc * 32 + l32;
        int kk = ks * 16 + half * 8 + b;
        ws[t] = f2bf(w1[o * 64 + kk]);
    } else if (t < 40960) {
        int idx = t - 24576;
        int lo = idx >= 8192;
        if (lo) idx -= 8192;
        int b = idx & 7, ln = (idx >> 3) & 63, ks = (idx >> 9) & 7, mtp = idx >> 12;
        int l32 = ln & 31, half = ln >> 5;
        int o = mtp * 32 + l32;
        int kk = ks * 16 + half * 8 + b;
        float v = wout[o * 128 + kk];
        unsigned short hi = f2bf(v);
        ws[t] = lo ? f2bf(v - bf2f(hi)) : hi;
    }
}

__global__ __launch_bounds__(NTHREADS, 4)
void fsas_fused(const float* __restrict__ x,
                const float* __restrict__ wdw,   // [384][3][3]
                const unsigned short* __restrict__ wsu,
                const float* __restrict__ lnw,
                const float* __restrict__ lnb,
                float* __restrict__ out)
{
    __shared__ unsigned short su[SMEM_U];

    const int tid = threadIdx.x;
    const int wv  = tid >> 6;      // 0..7
    const int ln  = tid & 63;
    const int l32 = ln & 31, half = ln >> 5;
    // XCD-aware swizzle: 4096 blocks, 8 XCDs round-robin on dispatch index.
    const int lin  = (blockIdx.z * 32 + blockIdx.y) * 32 + blockIdx.x;
    const int orig = (lin & 7) * 512 + (lin >> 3);
    const int pw = orig & 31;
    const int ph = (orig >> 5) & 31;
    const int b  = orig >> 10;
    const int h0  = ph * 8;
    const int w0  = pw * 8;

    // ---- 1) x tile (10x10 + halo) -> bf16 B-frags, pos-major: each unit packs
    //         8 channels at one pixel -> ONE contiguous b128 store (conflict-free)
    for (int it = 0; it < 2; ++it) {
        int u = tid + it * NTHREADS;      // 0..1023
        int pos = u & 127, grp = u >> 7;  // grp = channel octet 0..7
        uint4 o4 = {0u, 0u, 0u, 0u};
        if (pos < 100) {
            int r = pos / 10, q = pos - r * 10;
            int h = h0 - 1 + r, w = w0 - 1 + q;
            if ((unsigned)h < (unsigned)HH && (unsigned)w < (unsigned)WW) {
                const float* xp = x + ((size_t)(b * 64 + grp * 8) * HH + h) * WW + w;
                unsigned pk[4];
#pragma unroll
                for (int k = 0; k < 4; ++k) {
                    float v0 = xp[(2 * k)     * (HH * WW)];
                    float v1 = xp[(2 * k + 1) * (HH * WW)];
                    pk[k] = (unsigned)f2bf(v0) | ((unsigned)f2bf(v1) << 16);
                }
                o4.x = pk[0]; o4.y = pk[1]; o4.z = pk[2]; o4.w = pk[3];
            }
        }
        int lane = (pos & 31) + 32 * (grp & 1);
        int nt = pos >> 5, ks = grp >> 1;
        *(uint4*)(su + XF + ((nt * 4 + ks) * 64 + lane) * 8) = o4;
    }
    __syncthreads();

    // ---- 2) six half-rounds: MFMA (64 out-ch) + depthwise 3x3 ----
    const s16x8* waf = (const s16x8*)wsu;
    const int mt2 = wv & 1, nt = (wv >> 1) & 3;
    const int pos = nt * 32 + l32;
    const int r10 = pos / 10, c10 = pos - r10 * 10;
    const int posoff = r10 * 12 + c10;
    const bool pvalid = pos < 100;

    // Hoist the (round-invariant) B-fragments into registers; XF LDS dies here.
    s16x8 breg[4];
#pragma unroll
    for (int ks = 0; ks < 4; ++ks)
        breg[ks] = *(const s16x8*)(su + XF + ((nt * 4 + ks) * 64 + ln) * 8);
    __syncthreads();   // all breg reads done before rnd-0 HID overwrites XF

    uint4 vA, vB;      // V channels (oc) and (64+oc), row py — kept in registers
    const int dw_oc = tid >> 3, dw_py = tid & 7;

#pragma unroll
    for (int rnd = 0; rnd < 6; ++rnd) {
        {
            int mtc = rnd * 2 + mt2;
            f32x16 acc = {};
#pragma unroll
            for (int ks = 0; ks < 4; ++ks) {
                s16x8 afr = waf[(mtc * 4 + ks) * 64 + ln];
                acc = __builtin_amdgcn_mfma_f32_32x32x16_bf16(afr, breg[ks], acc, 0, 0, 0);
            }
            if (pvalid) {
#pragma unroll
                for (int rr = 0; rr < 16; ++rr) {
                    int o_l = mt2 * 32 + (rr & 3) + 8 * (rr >> 2) + 4 * half;
                    su[HIDA + o_l * 120 + posoff] = f2h(acc[rr]);
                }
            }
        }
        __syncthreads();
        {
            int oc = dw_oc, py = dw_py;
            // depthwise weights packed as f16 pairs: (w0,w1) and (w2,0) per row
            const float* wr = wdw + (rnd * 64 + oc) * 9;
            unsigned w01[3], w2z[3];
#pragma unroll
            for (int r3 = 0; r3 < 3; ++r3) {
                w01[r3] = (unsigned)f2h(wr[3 * r3]) | ((unsigned)f2h(wr[3 * r3 + 1]) << 16);
                w2z[r3] = (unsigned)f2h(wr[3 * r3 + 2]);
            }
            const unsigned short* hb = su + HIDA + oc * 120 + py * 12;
            float o_[8] = {0.f,0.f,0.f,0.f,0.f,0.f,0.f,0.f};
#pragma unroll
            for (int r3 = 0; r3 < 3; ++r3) {
                uint2 ua = *(const uint2*)(hb + r3 * 12);
                uint2 ub = *(const uint2*)(hb + r3 * 12 + 4);
                uint2 uc = *(const uint2*)(hb + r3 * 12 + 8);
                unsigned W[6] = {ua.x, ua.y, ub.x, ub.y, uc.x, uc.y};
                unsigned A[5];
#pragma unroll
                for (int k = 0; k < 5; ++k)
                    A[k] = __builtin_amdgcn_alignbit(W[k + 1], W[k], 16);
#pragma unroll
                for (int px = 0; px < 8; px += 2) {
                    int m = px >> 1;
                    o_[px]     = fdot2(w01[r3], W[m], fdot2(w2z[r3], W[m + 1], o_[px]));
                    o_[px + 1] = fdot2(w01[r3], A[m], fdot2(w2z[r3], A[m + 1], o_[px + 1]));
                }
            }
            uint4 o4;
            o4.x = (unsigned)f2h(o_[0]) | ((unsigned)f2h(o_[1]) << 16);
            o4.y = (unsigned)f2h(o_[2]) | ((unsigned)f2h(o_[3]) << 16);
            o4.z = (unsigned)f2h(o_[4]) | ((unsigned)f2h(o_[5]) << 16);
            o4.w = (unsigned)f2h(o_[6]) | ((unsigned)f2h(o_[7]) << 16);
            if (rnd < 4) {
                // q (rnds 0-1) and k (rnds 2-3) -> LDS (regions B and C, stride CST)
                int buf = rnd >> 1;
                int cb  = (rnd & 1) * 64 + oc;
                int cs  = cb & 7;
                *(uint4*)(su + Q_U + buf * 9216 + cb * CST + ((py ^ cs) * 8)) = o4;
            } else if (rnd == 4) {
                vA = o4;                     // v channel oc
            } else {
                vB = o4;                     // v channel 64+oc
            }
        }
        // WAR fence: next round's MFMA overwrites HID that this dw just read.
        if (rnd < 5) __syncthreads();
    }
    __syncthreads();   // fences rnd-5 HID reads before CORR overwrites region A

    // ---- 3) 8x8 circular conv via v_dot2_f32_f16; thread (oc,py): row py of
    //         channels oc and 64+oc. Skewed Q/K rows spread banks per channel. ----
    {
        int oc = dw_oc, py = dw_py;
#pragma unroll
        for (int cc = 0; cc < 2; ++cc) {
            int c = oc + cc * 64, cs = c & 7;
            const unsigned short* qr = su + Q_U + c * CST;
            const unsigned short* kr = su + K_U + c * CST;
            float o0[8] = {0.f,0.f,0.f,0.f,0.f,0.f,0.f,0.f};
#pragma unroll
            for (int a = 0; a < 8; ++a) {
                uint4 uq = *(const uint4*)(qr + ((a ^ cs) * 8));
                int k0 = (py - a) & 7;
                uint4 uk = *(const uint4*)(kr + ((k0 ^ cs) * 8));
                unsigned qw[4] = {uq.x, uq.y, uq.z, uq.w};
                unsigned kw[4] = {uk.x, uk.y, uk.z, uk.w};
                unsigned kr0[8];
#pragma unroll
                for (int p = 0; p < 4; ++p) {
                    kr0[2 * p]     = __builtin_amdgcn_perm(kw[(p + 3) & 3], kw[p], 0x07060100u);
                    kr0[2 * p + 1] = __builtin_amdgcn_alignbit(kw[p], kw[p], 16);
                }
#pragma unroll
                for (int j = 0; j < 8; ++j) {
#pragma unroll
                    for (int p = 0; p < 4; ++p)
                        o0[j] = fdot2(qw[p], kr0[(j - 2 * p) & 7], o0[j]);
                }
            }
            uint4 a4;
            a4.x = (unsigned)f2h(o0[0]) | ((unsigned)f2h(o0[1]) << 16);
            a4.y = (unsigned)f2h(o0[2]) | ((unsigned)f2h(o0[3]) << 16);
            a4.z = (unsigned)f2h(o0[4]) | ((unsigned)f2h(o0[5]) << 16);
            a4.w = (unsigned)f2h(o0[6]) | ((unsigned)f2h(o0[7]) << 16);
            *(uint4*)(su + CORRU + c * 64 + ((py ^ cs) * 8)) = a4;
        }
    }
    __syncthreads();

    // ---- 4) LayerNorm stats: 8 partial groups x 64 px (RED aliases dead Q) ----
    {
        float* redF = (float*)(su + REDU);
        int px = tid & 63, grp = tid >> 6;     // grp 0..7
        int prow = px >> 3, pcol = px & 7;
        float s = 0.f, s2 = 0.f;
#pragma unroll
        for (int i = 0; i < 16; ++i) {
            int c = i * 8 + grp;
            float v = (float)__builtin_bit_cast(_Float16,
                        su[CORRU + c * 64 + ((prow ^ (c & 7)) * 8) + pcol]);
            s += v; s2 += v * v;
        }
        redF[grp * 64 + px] = s;
        redF[512 + grp * 64 + px] = s2;
    }
    __syncthreads();
    if (tid < 64) {
        float* redF = (float*)(su + REDU);
        float s = 0.f, s2 = 0.f;
#pragma unroll
        for (int g = 0; g < 8; ++g) {
            s  += redF[g * 64 + tid];
            s2 += redF[512 + g * 64 + tid];
        }
        float m = s * (1.f / 128.f);
        float var = s2 * (1.f / 128.f) - m * m;
        ((float*)(su + MU_U))[tid] = m;
        ((float*)(su + RS_U))[tid] = rsqrtf(var + 1e-5f);
    }
    __syncthreads();

    // ---- 5) normalize + affine + gate(V regs) -> bf16 B-frags (BFR aliases Q/RED) ----
    {
        int oc = dw_oc, py = dw_py;
        const float* muF = (const float*)(su + MU_U);
        const float* rsF = (const float*)(su + RS_U);
        float4 m0 = *(const float4*)(muF + py * 8);
        float4 m1 = *(const float4*)(muF + py * 8 + 4);
        float4 r0 = *(const float4*)(rsF + py * 8);
        float4 r1 = *(const float4*)(rsF + py * 8 + 4);
        float mm[8] = {m0.x, m0.y, m0.z, m0.w, m1.x, m1.y, m1.z, m1.w};
        float rr[8] = {r0.x, r0.y, r0.z, r0.w, r1.x, r1.y, r1.z, r1.w};
#pragma unroll
        for (int cc = 0; cc < 2; ++cc) {
            int c = oc + cc * 64, cs = c & 7;
            uint4 cu = *(const uint4*)(su + CORRU + c * 64 + ((py ^ cs) * 8));
            h16x8 ch = __builtin_bit_cast(h16x8, cu);
            h16x8 vh = __builtin_bit_cast(h16x8, cc ? vB : vA);
            float wc = lnw[c], bc = lnb[c];
            int base = BFRU + (((py >> 2) * 8 + (c >> 4)) * 64 + 8 * (py & 3) + 32 * ((c >> 3) & 1)) * 8 + (c & 7);
#pragma unroll
            for (int j = 0; j < 8; ++j) {
                float t = (((float)ch[j] - mm[j]) * rr[j] * wc + bc) * (float)vh[j];
                su[base + j * 8] = f2bf(t);
            }
        }
    }
    __syncthreads();

    // ---- 6) projection 128 -> 64: 4 waves, full-K, single accumulator,
    //         direct f32 global store ----
    if (wv < 4) {
        int mtp = wv & 1, ntp = wv >> 1;
        const s16x8* whi = (const s16x8*)(wsu + 24576);
        const s16x8* wlo = (const s16x8*)(wsu + 32768);
        f32x16 acc = {};
#pragma unroll
        for (int ks = 0; ks < 8; ++ks) {
            s16x8 bfr = *(const s16x8*)(su + BFRU + ((ntp * 8 + ks) * 64 + ln) * 8);
            s16x8 ah  = whi[(mtp * 8 + ks) * 64 + ln];
            acc = __builtin_amdgcn_mfma_f32_32x32x16_bf16(ah, bfr, acc, 0, 0, 0);
            s16x8 al  = wlo[(mtp * 8 + ks) * 64 + ln];
            acc = __builtin_amdgcn_mfma_f32_32x32x16_bf16(al, bfr, acc, 0, 0, 0);
        }
        int px = ntp * 32 + l32;
        int py = px >> 3, wx = px & 7;
#pragma unroll
        for (int r = 0; r < 16; ++r) {
            int row = (r >> 2) * 8 + half * 4 + (r & 3);
            int o = mtp * 32 + row;
            out[(((size_t)(b * 64 + o) * HH) + h0 + py) * WW + w0 + wx] = acc[r];
        }
    }
}

extern "C" void kernel_launch(void* const* d_in, const int* in_sizes, int n_in,
                              void* d_out, int out_size, void* d_ws, size_t ws_size,
                              hipStream_t stream) {
    const float* x    = (const float*)d_in[0];
    const float* w1   = (const float*)d_in[1];
    const float* wdw  = (const float*)d_in[2];
    const float* wout = (const float*)d_in[3];
    const float* lnw  = (const float*)d_in[4];
    const float* lnb  = (const float*)d_in[5];
    float* o = (float*)d_out;
    unsigned short* ws = (unsigned short*)d_ws;

    fsas_prepack<<<160, 256, 0, stream>>>(w1, wout, ws);
    dim3 grid(32, 32, NB);
    fsas_fused<<<grid, dim3(NTHREADS), 0, stream>>>(x, wdw, ws, lnw, lnb, o);
}

// Round 8
// 260.116 us; speedup vs baseline: 1.2108x; 1.0623x over previous
//
#include <hip/hip_runtime.h>

#define NTHREADS 512

// Geometry (fixed by the reference)
#define NB   4
#define HH   256
#define WW   256

// u16-unit LDS offsets. Total 40704 u16 = 81,408 B -> 2 blocks/CU (162,816 <= 163,840)
// Region A [0..8191]:      XF (x B-frags) -> HIDA (even rnds) -> CORR
// Region B [8192..16383]:  Q (128ch x 64) -> RED -> BFR
// Region C [16384..32767]: KP (128ch x 128: 8 rows x 8 paired u32, row^cs XOR)
// Region D [32768..40447]: HIDB (odd rnds)
#define XF     0
#define HIDA   0        // even-round HID buffer, aliases XF
#define Q_U    8192     // q: 128ch x 64 u16, (slot^cs)*8 XOR      (dead after stage 3)
#define KP_U   16384    // k paired: 128ch x 128 u16, (row^cs)*16  (dead after stage 3)
#define HIDB   32768    // odd-round HID buffer (7680 u16)
#define CORRU  0        // 8192 u16 f16 (alias A; HIDA dead after rnd-4 dw + rnd-5 bar)
#define REDU   8192     // 4096 u16 f32 partials (alias Q; Q dead after stage 3)
#define BFRU   8192     // 8192 u16 bf16 gated B-frags (alias Q/RED; RED dead after mu/rs)
#define MU_U   40448    // 128 u16 = 64 f32
#define RS_U   40576    // 128 u16 = 64 f32
#define SMEM_U 40704

typedef short s16x8 __attribute__((ext_vector_type(8)));
typedef float f32x16 __attribute__((ext_vector_type(16)));
typedef _Float16 h16x8 __attribute__((ext_vector_type(8)));
typedef _Float16 h16x4 __attribute__((ext_vector_type(4)));
typedef _Float16 h16x2 __attribute__((ext_vector_type(2)));

__device__ inline unsigned short f2bf(float f) {      // RNE f32 -> bf16
    unsigned u = __builtin_bit_cast(unsigned, f);
    u += 0x7FFFu + ((u >> 16) & 1u);
    return (unsigned short)(u >> 16);
}
__device__ inline float bf2f(unsigned short s) {
    return __builtin_bit_cast(float, (unsigned)s << 16);
}
__device__ inline unsigned short f2h(float f) {
    _Float16 h = (_Float16)f;
    return __builtin_bit_cast(unsigned short, h);
}

// v_dot2_f32_f16: d = a.lo*b.lo + a.hi*b.hi + c  (f16 mul, f32 accumulate)
__device__ inline float fdot2(unsigned a, unsigned b, float c) {
#if __has_builtin(__builtin_amdgcn_fdot2)
    return __builtin_amdgcn_fdot2(__builtin_bit_cast(h16x2, a),
                                  __builtin_bit_cast(h16x2, b), c, false);
#else
    h16x2 av = __builtin_bit_cast(h16x2, a);
    h16x2 bv = __builtin_bit_cast(h16x2, b);
    return c + (float)av[0] * (float)bv[0] + (float)av[1] * (float)bv[1];
#endif
}

// ---- prepack: w1 + wout(hi/lo) -> bf16 MFMA A-fragment order in d_ws ----
__global__ __launch_bounds__(256)
void fsas_prepack(const float* __restrict__ w1, const float* __restrict__ wout,
                  unsigned short* __restrict__ ws)
{
    int t = blockIdx.x * 256 + threadIdx.x;   // 0..40959
    if (t < 24576) {
        int b = t & 7, ln = (t >> 3) & 63, ks = (t >> 9) & 3, mtc = t >> 11;
        int l32 = ln & 31, half = ln >> 5;
        int o = mtc * 32 + l32;
        int kk = ks * 16 + half * 8 + b;
        ws[t] = f2bf(w1[o * 64 + kk]);
    } else if (t < 40960) {
        int idx = t - 24576;
        int lo = idx >= 8192;
        if (lo) idx -= 8192;
        int b = idx & 7, ln = (idx >> 3) & 63, ks = (idx >> 9) & 7, mtp = idx >> 12;
        int l32 = ln & 31, half = ln >> 5;
        int o = mtp * 32 + l32;
        int kk = ks * 16 + half * 8 + b;
        float v = wout[o * 128 + kk];
        unsigned short hi = f2bf(v);
        ws[t] = lo ? f2bf(v - bf2f(hi)) : hi;
    }
}

__global__ __launch_bounds__(NTHREADS, 4)
void fsas_fused(const float* __restrict__ x,
                const float* __restrict__ wdw,   // [384][3][3]
                const unsigned short* __restrict__ wsu,
                const float* __restrict__ lnw,
                const float* __restrict__ lnb,
                float* __restrict__ out)
{
    __shared__ unsigned short su[SMEM_U];

    const int tid = threadIdx.x;
    const int wv  = tid >> 6;      // 0..7
    const int ln  = tid & 63;
    const int l32 = ln & 31, half = ln >> 5;
    // XCD-aware swizzle: 4096 blocks, 8 XCDs round-robin on dispatch index.
    const int lin  = (blockIdx.z * 32 + blockIdx.y) * 32 + blockIdx.x;
    const int orig = (lin & 7) * 512 + (lin >> 3);
    const int pw = orig & 31;
    const int ph = (orig >> 5) & 31;
    const int b  = orig >> 10;
    const int h0  = ph * 8;
    const int w0  = pw * 8;

    const int dw_oc = tid >> 3, dw_py = tid & 7;

    // ---- 0) hoist depthwise weights for all 6 rounds (packed f16) ----
    // Issued before stage-1 LDS work so the global loads overlap it.
    unsigned w01[6][3], w2z[6][3];
#pragma unroll
    for (int rnd = 0; rnd < 6; ++rnd) {
        const float* wr = wdw + (rnd * 64 + dw_oc) * 9;
#pragma unroll
        for (int r3 = 0; r3 < 3; ++r3) {
            w01[rnd][r3] = (unsigned)f2h(wr[3 * r3]) | ((unsigned)f2h(wr[3 * r3 + 1]) << 16);
            w2z[rnd][r3] = (unsigned)f2h(wr[3 * r3 + 2]);
        }
    }

    // ---- 1) x tile (10x10 + halo) -> bf16 B-frags, pos-major: each unit packs
    //         8 channels at one pixel -> ONE contiguous b128 store (conflict-free)
    for (int it = 0; it < 2; ++it) {
        int u = tid + it * NTHREADS;      // 0..1023
        int pos = u & 127, grp = u >> 7;  // grp = channel octet 0..7
        uint4 o4 = {0u, 0u, 0u, 0u};
        if (pos < 100) {
            int r = pos / 10, q = pos - r * 10;
            int h = h0 - 1 + r, w = w0 - 1 + q;
            if ((unsigned)h < (unsigned)HH && (unsigned)w < (unsigned)WW) {
                const float* xp = x + ((size_t)(b * 64 + grp * 8) * HH + h) * WW + w;
                unsigned pk[4];
#pragma unroll
                for (int k = 0; k < 4; ++k) {
                    float v0 = xp[(2 * k)     * (HH * WW)];
                    float v1 = xp[(2 * k + 1) * (HH * WW)];
                    pk[k] = (unsigned)f2bf(v0) | ((unsigned)f2bf(v1) << 16);
                }
                o4.x = pk[0]; o4.y = pk[1]; o4.z = pk[2]; o4.w = pk[3];
            }
        }
        int lane = (pos & 31) + 32 * (grp & 1);
        int nt = pos >> 5, ks = grp >> 1;
        *(uint4*)(su + XF + ((nt * 4 + ks) * 64 + lane) * 8) = o4;
    }
    __syncthreads();

    // ---- 2) six half-rounds: MFMA (64 out-ch) + depthwise 3x3, HID dbuf ----
    const s16x8* waf = (const s16x8*)wsu;
    const int mt2 = wv & 1, nt = (wv >> 1) & 3;
    const int pos = nt * 32 + l32;
    const int r10 = pos / 10, c10 = pos - r10 * 10;
    const int posoff = r10 * 12 + c10;
    const bool pvalid = pos < 100;

    // Hoist the (round-invariant) B-fragments into registers; XF LDS dies here.
    s16x8 breg[4];
#pragma unroll
    for (int ks = 0; ks < 4; ++ks)
        breg[ks] = *(const s16x8*)(su + XF + ((nt * 4 + ks) * 64 + ln) * 8);
    __syncthreads();   // all breg reads done before rnd-0 HID overwrites XF

    uint4 vA, vB;      // V channels (oc) and (64+oc), row py — kept in registers

#pragma unroll
    for (int rnd = 0; rnd < 6; ++rnd) {
        const int hid_base = (rnd & 1) ? HIDB : HIDA;   // double-buffered scratch
        {
            int mtc = rnd * 2 + mt2;
            f32x16 acc = {};
#pragma unroll
            for (int ks = 0; ks < 4; ++ks) {
                s16x8 afr = waf[(mtc * 4 + ks) * 64 + ln];
                acc = __builtin_amdgcn_mfma_f32_32x32x16_bf16(afr, breg[ks], acc, 0, 0, 0);
            }
            if (pvalid) {
#pragma unroll
                for (int rr = 0; rr < 16; ++rr) {
                    int o_l = mt2 * 32 + (rr & 3) + 8 * (rr >> 2) + 4 * half;
                    su[hid_base + o_l * 120 + posoff] = f2h(acc[rr]);
                }
            }
        }
        __syncthreads();
        // dw reads buf[rnd&1]; rnd+2's MFMA overwrite of this buffer is fenced
        // by the barrier inside round rnd+1 -> no trailing barrier needed.
        {
            int oc = dw_oc, py = dw_py;
            const unsigned short* hb = su + hid_base + oc * 120 + py * 12;
            float o_[8] = {0.f,0.f,0.f,0.f,0.f,0.f,0.f,0.f};
#pragma unroll
            for (int r3 = 0; r3 < 3; ++r3) {
                uint2 ua = *(const uint2*)(hb + r3 * 12);
                uint2 ub = *(const uint2*)(hb + r3 * 12 + 4);
                uint2 uc = *(const uint2*)(hb + r3 * 12 + 8);
                unsigned W[5] = {ua.x, ua.y, ub.x, ub.y, uc.x};
                unsigned A[5];
#pragma unroll
                for (int k = 0; k < 4; ++k)
                    A[k] = __builtin_amdgcn_alignbit(W[k + 1], W[k], 16);
                // A[4] pairs (col9, col8): hi half multiplied by 0.0 below, and
                // col10 (the unwritten 12-stride pad -- can be NaN garbage in
                // the fresh HIDB region) is never read. NaN-safety fix (r7 bug).
                A[4] = __builtin_amdgcn_alignbit(W[4], W[4], 16);
#pragma unroll
                for (int px = 0; px < 8; px += 2) {
                    int m = px >> 1;
                    o_[px]     = fdot2(w01[rnd][r3], W[m], fdot2(w2z[rnd][r3], W[m + 1], o_[px]));
                    o_[px + 1] = fdot2(w01[rnd][r3], A[m], fdot2(w2z[rnd][r3], A[m + 1], o_[px + 1]));
                }
            }
            uint4 o4;
            o4.x = (unsigned)f2h(o_[0]) | ((unsigned)f2h(o_[1]) << 16);
            o4.y = (unsigned)f2h(o_[2]) | ((unsigned)f2h(o_[3]) << 16);
            o4.z = (unsigned)f2h(o_[4]) | ((unsigned)f2h(o_[5]) << 16);
            o4.w = (unsigned)f2h(o_[6]) | ((unsigned)f2h(o_[7]) << 16);
            int cb = (rnd & 1) * 64 + oc;
            int cs = cb & 7;
            if (rnd < 2) {
                // q -> region B, 64 u16/channel, slot-XOR layout
                *(uint4*)(su + Q_U + cb * 64 + ((py ^ cs) * 8)) = o4;
            } else if (rnd < 4) {
                // k -> paired layout: kp[m] = (k[m], k[(m-1)&7]) per row, so
                // stage 3 needs zero prep. 2 x b128 per row, row-XOR keeps banks spread.
                unsigned kw[4] = {o4.x, o4.y, o4.z, o4.w};
                uint4 p0, p1;
                p0.x = __builtin_amdgcn_perm(kw[3], kw[0], 0x07060100u);
                p0.y = __builtin_amdgcn_alignbit(kw[0], kw[0], 16);
                p0.z = __builtin_amdgcn_perm(kw[0], kw[1], 0x07060100u);
                p0.w = __builtin_amdgcn_alignbit(kw[1], kw[1], 16);
                p1.x = __builtin_amdgcn_perm(kw[1], kw[2], 0x07060100u);
                p1.y = __builtin_amdgcn_alignbit(kw[2], kw[2], 16);
                p1.z = __builtin_amdgcn_perm(kw[2], kw[3], 0x07060100u);
                p1.w = __builtin_amdgcn_alignbit(kw[3], kw[3], 16);
                unsigned short* kd = su + KP_U + cb * 128 + ((py ^ cs) * 16);
                *(uint4*)kd = p0;
                *(uint4*)(kd + 8) = p1;
            } else if (rnd == 4) {
                vA = o4;                     // v channel oc
            } else {
                vB = o4;                     // v channel 64+oc
            }
        }
    }
    __syncthreads();   // fences rnd-4/5 HID reads + q/kp writes before stage 3

    // ---- 3) 8x8 circular conv via v_dot2_f32_f16; thread (oc,py): row py of
    //         channels oc and 64+oc. K pre-paired -> zero in-loop prep. ----
    {
        int oc = dw_oc, py = dw_py;
#pragma unroll
        for (int cc = 0; cc < 2; ++cc) {
            int c = oc + cc * 64, cs = c & 7;
            const unsigned short* qr = su + Q_U  + c * 64;
            const unsigned short* kr = su + KP_U + c * 128;
            float o0[8] = {0.f,0.f,0.f,0.f,0.f,0.f,0.f,0.f};
#pragma unroll
            for (int a = 0; a < 8; ++a) {
                uint4 uq = *(const uint4*)(qr + ((a ^ cs) * 8));
                int k0 = (py - a) & 7;
                const unsigned short* kpr = kr + ((k0 ^ cs) * 16);
                uint4 uk0 = *(const uint4*)(kpr);
                uint4 uk1 = *(const uint4*)(kpr + 8);
                unsigned qw[4] = {uq.x, uq.y, uq.z, uq.w};
                unsigned kp[8] = {uk0.x, uk0.y, uk0.z, uk0.w, uk1.x, uk1.y, uk1.z, uk1.w};
#pragma unroll
                for (int j = 0; j < 8; ++j) {
#pragma unroll
                    for (int p = 0; p < 4; ++p)
                        o0[j] = fdot2(qw[p], kp[(j - 2 * p) & 7], o0[j]);
                }
            }
            uint4 a4;
            a4.x = (unsigned)f2h(o0[0]) | ((unsigned)f2h(o0[1]) << 16);
            a4.y = (unsigned)f2h(o0[2]) | ((unsigned)f2h(o0[3]) << 16);
            a4.z = (unsigned)f2h(o0[4]) | ((unsigned)f2h(o0[5]) << 16);
            a4.w = (unsigned)f2h(o0[6]) | ((unsigned)f2h(o0[7]) << 16);
            *(uint4*)(su + CORRU + c * 64 + ((py ^ cs) * 8)) = a4;
        }
    }
    __syncthreads();

    // ---- 4) LayerNorm stats: 8 partial groups x 64 px (RED aliases dead Q) ----
    {
        float* redF = (float*)(su + REDU);
        int px = tid & 63, grp = tid >> 6;     // grp 0..7
        int prow = px >> 3, pcol = px & 7;
        float s = 0.f, s2 = 0.f;
#pragma unroll
        for (int i = 0; i < 16; ++i) {
            int c = i * 8 + grp;
            float v = (float)__builtin_bit_cast(_Float16,
                        su[CORRU + c * 64 + ((prow ^ (c & 7)) * 8) + pcol]);
            s += v; s2 += v * v;
        }
        redF[grp * 64 + px] = s;
        redF[512 + grp * 64 + px] = s2;
    }
    __syncthreads();
    if (tid < 64) {
        float* redF = (float*)(su + REDU);
        float s = 0.f, s2 = 0.f;
#pragma unroll
        for (int g = 0; g < 8; ++g) {
            s  += redF[g * 64 + tid];
            s2 += redF[512 + g * 64 + tid];
        }
        float m = s * (1.f / 128.f);
        float var = s2 * (1.f / 128.f) - m * m;
        ((float*)(su + MU_U))[tid] = m;
        ((float*)(su + RS_U))[tid] = rsqrtf(var + 1e-5f);
    }
    __syncthreads();

    // ---- 5) normalize + affine + gate(V regs) -> bf16 B-frags (BFR aliases Q/RED) ----
    {
        int oc = dw_oc, py = dw_py;
        const float* muF = (const float*)(su + MU_U);
        const float* rsF = (const float*)(su + RS_U);
        float4 m0 = *(const float4*)(muF + py * 8);
        float4 m1 = *(const float4*)(muF + py * 8 + 4);
        float4 r0 = *(const float4*)(rsF + py * 8);
        float4 r1 = *(const float4*)(rsF + py * 8 + 4);
        float mm[8] = {m0.x, m0.y, m0.z, m0.w, m1.x, m1.y, m1.z, m1.w};
        float rr[8] = {r0.x, r0.y, r0.z, r0.w, r1.x, r1.y, r1.z, r1.w};
#pragma unroll
        for (int cc = 0; cc < 2; ++cc) {
            int c = oc + cc * 64, cs = c & 7;
            uint4 cu = *(const uint4*)(su + CORRU + c * 64 + ((py ^ cs) * 8));
            h16x8 ch = __builtin_bit_cast(h16x8, cu);
            h16x8 vh = __builtin_bit_cast(h16x8, cc ? vB : vA);
            float wc = lnw[c], bc = lnb[c];
            int base = BFRU + (((py >> 2) * 8 + (c >> 4)) * 64 + 8 * (py & 3) + 32 * ((c >> 3) & 1)) * 8 + (c & 7);
#pragma unroll
            for (int j = 0; j < 8; ++j) {
                float t = (((float)ch[j] - mm[j]) * rr[j] * wc + bc) * (float)vh[j];
                su[base + j * 8] = f2bf(t);
            }
        }
    }
    __syncthreads();

    // ---- 6) projection 128 -> 64: 4 waves, full-K, single accumulator,
    //         direct f32 global store ----
    if (wv < 4) {
        int mtp = wv & 1, ntp = wv >> 1;
        const s16x8* whi = (const s16x8*)(wsu + 24576);
        const s16x8* wlo = (const s16x8*)(wsu + 32768);
        f32x16 acc = {};
#pragma unroll
        for (int ks = 0; ks < 8; ++ks) {
            s16x8 bfr = *(const s16x8*)(su + BFRU + ((ntp * 8 + ks) * 64 + ln) * 8);
            s16x8 ah  = whi[(mtp * 8 + ks) * 64 + ln];
            acc = __builtin_amdgcn_mfma_f32_32x32x16_bf16(ah, bfr, acc, 0, 0, 0);
            s16x8 al  = wlo[(mtp * 8 + ks) * 64 + ln];
            acc = __builtin_amdgcn_mfma_f32_32x32x16_bf16(al, bfr, acc, 0, 0, 0);
        }
        int px = ntp * 32 + l32;
        int py = px >> 3, wx = px & 7;
#pragma unroll
        for (int r = 0; r < 16; ++r) {
            int row = (r >> 2) * 8 + half * 4 + (r & 3);
            int o = mtp * 32 + row;
            out[(((size_t)(b * 64 + o) * HH) + h0 + py) * WW + w0 + wx] = acc[r];
        }
    }
}

extern "C" void kernel_launch(void* const* d_in, const int* in_sizes, int n_in,
                              void* d_out, int out_size, void* d_ws, size_t ws_size,
                              hipStream_t stream) {
    const float* x    = (const float*)d_in[0];
    const float* w1   = (const float*)d_in[1];
    const float* wdw  = (const float*)d_in[2];
    const float* wout = (const float*)d_in[3];
    const float* lnw  = (const float*)d_in[4];
    const float* lnb  = (const float*)d_in[5];
    float* o = (float*)d_out;
    unsigned short* ws = (unsigned short*)d_ws;

    fsas_prepack<<<160, 256, 0, stream>>>(w1, wout, ws);
    dim3 grid(32, 32, NB);
    fsas_fused<<<grid, dim3(NTHREADS), 0, stream>>>(x, wdw, ws, lnw, lnb, o);
}

// Round 9
// 247.280 us; speedup vs baseline: 1.2736x; 1.0519x over previous
//
#include <hip/hip_runtime.h>

#define NTHREADS 512

// Geometry (fixed by the reference)
#define NB   4
#define HH   256
#define WW   256

// u16-unit LDS offsets. Total 40704 u16 = 81,408 B -> 2 blocks/CU (162,816 <= 163,840)
// Region A [0..8191]:      XF (x B-frags) -> HIDA (even rnds) -> CORR
// Region B [8192..16383]:  Q (128ch x 64) -> RED -> BFR
// Region C [16384..32767]: KP (128ch x 128: 8 rows x 8 paired u32, row^cs XOR)
// Region D [32768..40447]: HIDB (odd rnds)
#define XF     0
#define HIDA   0        // even-round HID buffer, aliases XF
#define Q_U    8192     // q: 128ch x 64 u16, (slot^cs)*8 XOR      (dead after stage 3)
#define KP_U   16384    // k paired: 128ch x 128 u16, (row^cs)*16  (dead after stage 3)
#define HIDB   32768    // odd-round HID buffer (7680 u16)
#define CORRU  0        // 8192 u16 f16 (alias A; HIDA dead after rnd-4 dw, fenced by bar5)
#define REDU   8192     // 4096 u16 f32 partials (alias Q; Q dead after stage 3)
#define BFRU   8192     // 8192 u16 bf16 gated B-frags (alias Q/RED; RED dead after mu/rs)
#define MU_U   40448    // 128 u16 = 64 f32
#define RS_U   40576    // 128 u16 = 64 f32
#define SMEM_U 40704

typedef short s16x8 __attribute__((ext_vector_type(8)));
typedef float f32x16 __attribute__((ext_vector_type(16)));
typedef _Float16 h16x8 __attribute__((ext_vector_type(8)));
typedef _Float16 h16x4 __attribute__((ext_vector_type(4)));
typedef _Float16 h16x2 __attribute__((ext_vector_type(2)));

__device__ inline unsigned short f2bf(float f) {      // RNE f32 -> bf16
    unsigned u = __builtin_bit_cast(unsigned, f);
    u += 0x7FFFu + ((u >> 16) & 1u);
    return (unsigned short)(u >> 16);
}
__device__ inline float bf2f(unsigned short s) {
    return __builtin_bit_cast(float, (unsigned)s << 16);
}
__device__ inline unsigned short f2h(float f) {
    _Float16 h = (_Float16)f;
    return __builtin_bit_cast(unsigned short, h);
}

// v_dot2_f32_f16: d = a.lo*b.lo + a.hi*b.hi + c  (f16 mul, f32 accumulate)
__device__ inline float fdot2(unsigned a, unsigned b, float c) {
#if __has_builtin(__builtin_amdgcn_fdot2)
    return __builtin_amdgcn_fdot2(__builtin_bit_cast(h16x2, a),
                                  __builtin_bit_cast(h16x2, b), c, false);
#else
    h16x2 av = __builtin_bit_cast(h16x2, a);
    h16x2 bv = __builtin_bit_cast(h16x2, b);
    return c + (float)av[0] * (float)bv[0] + (float)av[1] * (float)bv[1];
#endif
}

// ---- prepack: w1 + wout(hi/lo) -> bf16 MFMA A-fragment order in d_ws ----
__global__ __launch_bounds__(256)
void fsas_prepack(const float* __restrict__ w1, const float* __restrict__ wout,
                  unsigned short* __restrict__ ws)
{
    int t = blockIdx.x * 256 + threadIdx.x;   // 0..40959
    if (t < 24576) {
        int b = t & 7, ln = (t >> 3) & 63, ks = (t >> 9) & 3, mtc = t >> 11;
        int l32 = ln & 31, half = ln >> 5;
        int o = mtc * 32 + l32;
        int kk = ks * 16 + half * 8 + b;
        ws[t] = f2bf(w1[o * 64 + kk]);
    } else if (t < 40960) {
        int idx = t - 24576;
        int lo = idx >= 8192;
        if (lo) idx -= 8192;
        int b = idx & 7, ln = (idx >> 3) & 63, ks = (idx >> 9) & 7, mtp = idx >> 12;
        int l32 = ln & 31, half = ln >> 5;
        int o = mtp * 32 + l32;
        int kk = ks * 16 + half * 8 + b;
        float v = wout[o * 128 + kk];
        unsigned short hi = f2bf(v);
        ws[t] = lo ? f2bf(v - bf2f(hi)) : hi;
    }
}

__global__ __launch_bounds__(NTHREADS, 4)
void fsas_fused(const float* __restrict__ x,
                const float* __restrict__ wdw,   // [384][3][3]
                const unsigned short* __restrict__ wsu,
                const float* __restrict__ lnw,
                const float* __restrict__ lnb,
                float* __restrict__ out)
{
    __shared__ unsigned short su[SMEM_U];

    const int tid = threadIdx.x;
    const int wv  = tid >> 6;      // 0..7
    const int ln  = tid & 63;
    const int l32 = ln & 31, half = ln >> 5;
    // XCD-aware swizzle: 4096 blocks, 8 XCDs round-robin on dispatch index.
    const int lin  = (blockIdx.z * 32 + blockIdx.y) * 32 + blockIdx.x;
    const int orig = (lin & 7) * 512 + (lin >> 3);
    const int pw = orig & 31;
    const int ph = (orig >> 5) & 31;
    const int b  = orig >> 10;
    const int h0  = ph * 8;
    const int w0  = pw * 8;

    const int dw_oc = tid >> 3, dw_py = tid & 7;
    const int p6_mtp = wv & 1, p6_ntp = (wv >> 1) & 1;   // stage-6 tile coords

    // ---- 0) hoist depthwise weights for all 6 rounds (packed f16) ----
    // Issued before stage-1 LDS work so the global loads overlap it.
    unsigned w01[6][3], w2z[6][3];
#pragma unroll
    for (int rnd = 0; rnd < 6; ++rnd) {
        const float* wr = wdw + (rnd * 64 + dw_oc) * 9;
#pragma unroll
        for (int r3 = 0; r3 < 3; ++r3) {
            w01[rnd][r3] = (unsigned)f2h(wr[3 * r3]) | ((unsigned)f2h(wr[3 * r3 + 1]) << 16);
            w2z[rnd][r3] = (unsigned)f2h(wr[3 * r3 + 2]);
        }
    }

    // ---- 1) x tile (10x10 + halo) -> bf16 B-frags, pos-major: each unit packs
    //         8 channels at one pixel -> ONE contiguous b128 store (conflict-free)
    for (int it = 0; it < 2; ++it) {
        int u = tid + it * NTHREADS;      // 0..1023
        int pos = u & 127, grp = u >> 7;  // grp = channel octet 0..7
        uint4 o4 = {0u, 0u, 0u, 0u};
        if (pos < 100) {
            int r = pos / 10, q = pos - r * 10;
            int h = h0 - 1 + r, w = w0 - 1 + q;
            if ((unsigned)h < (unsigned)HH && (unsigned)w < (unsigned)WW) {
                const float* xp = x + ((size_t)(b * 64 + grp * 8) * HH + h) * WW + w;
                unsigned pk[4];
#pragma unroll
                for (int k = 0; k < 4; ++k) {
                    float v0 = xp[(2 * k)     * (HH * WW)];
                    float v1 = xp[(2 * k + 1) * (HH * WW)];
                    pk[k] = (unsigned)f2bf(v0) | ((unsigned)f2bf(v1) << 16);
                }
                o4.x = pk[0]; o4.y = pk[1]; o4.z = pk[2]; o4.w = pk[3];
            }
        }
        int lane = (pos & 31) + 32 * (grp & 1);
        int nt = pos >> 5, ks = grp >> 1;
        *(uint4*)(su + XF + ((nt * 4 + ks) * 64 + lane) * 8) = o4;
    }
    __syncthreads();

    // ---- 2) six half-rounds: MFMA (64 out-ch) + depthwise 3x3, HID dbuf,
    //         software-pipelined A-fragment loads (prefetch across barrier) ----
    const s16x8* waf = (const s16x8*)wsu;
    const int mt2 = wv & 1, nt = (wv >> 1) & 3;
    const int pos = nt * 32 + l32;
    const int r10 = pos / 10, c10 = pos - r10 * 10;
    const int posoff = r10 * 12 + c10;
    const bool pvalid = pos < 100;

    // Hoist the (round-invariant) B-fragments into registers; XF LDS dies here.
    s16x8 breg[4];
#pragma unroll
    for (int ks = 0; ks < 4; ++ks)
        breg[ks] = *(const s16x8*)(su + XF + ((nt * 4 + ks) * 64 + ln) * 8);
    __syncthreads();   // all breg reads done before rnd-0 HID overwrites XF

    uint4 vA, vB;      // V channels (oc) and (64+oc), row py — kept in registers

    // prefetch round-0 A-fragments
    s16x8 wa[4], wn[4];
#pragma unroll
    for (int ks = 0; ks < 4; ++ks)
        wa[ks] = waf[(mt2 * 4 + ks) * 64 + ln];

#pragma unroll
    for (int rnd = 0; rnd < 6; ++rnd) {
        const int hid_base = (rnd & 1) ? HIDB : HIDA;   // double-buffered scratch
        {
            f32x16 acc = {};
#pragma unroll
            for (int ks = 0; ks < 4; ++ks)
                acc = __builtin_amdgcn_mfma_f32_32x32x16_bf16(wa[ks], breg[ks], acc, 0, 0, 0);
            // prefetch NEXT round's A-fragments before the barrier so the
            // global loads complete under the HID stores + barrier drain
            // (compiler won't hoist global loads across s_barrier itself).
            if (rnd < 5) {
                int mtc = (rnd + 1) * 2 + mt2;
#pragma unroll
                for (int ks = 0; ks < 4; ++ks)
                    wn[ks] = waf[(mtc * 4 + ks) * 64 + ln];
            }
            if (pvalid) {
#pragma unroll
                for (int rr = 0; rr < 16; ++rr) {
                    int o_l = mt2 * 32 + (rr & 3) + 8 * (rr >> 2) + 4 * half;
                    su[hid_base + o_l * 120 + posoff] = f2h(acc[rr]);
                }
            }
        }
        __syncthreads();
        // dw reads buf[rnd&1]; rnd+2's MFMA overwrite of this buffer is fenced
        // by the barrier inside round rnd+1 -> no trailing barrier needed.
        {
            int oc = dw_oc, py = dw_py;
            const unsigned short* hb = su + hid_base + oc * 120 + py * 12;
            float o_[8] = {0.f,0.f,0.f,0.f,0.f,0.f,0.f,0.f};
#pragma unroll
            for (int r3 = 0; r3 < 3; ++r3) {
                uint2 ua = *(const uint2*)(hb + r3 * 12);
                uint2 ub = *(const uint2*)(hb + r3 * 12 + 4);
                uint2 uc = *(const uint2*)(hb + r3 * 12 + 8);
                unsigned W[5] = {ua.x, ua.y, ub.x, ub.y, uc.x};
                unsigned A[5];
#pragma unroll
                for (int k = 0; k < 4; ++k)
                    A[k] = __builtin_amdgcn_alignbit(W[k + 1], W[k], 16);
                // A[4] pairs (col9, col8): hi half multiplied by 0.0 below;
                // col10 (unwritten 12-stride pad, garbage in fresh LDS) is
                // never read. NaN-safety fix (r7 bug).
                A[4] = __builtin_amdgcn_alignbit(W[4], W[4], 16);
#pragma unroll
                for (int px = 0; px < 8; px += 2) {
                    int m = px >> 1;
                    o_[px]     = fdot2(w01[rnd][r3], W[m], fdot2(w2z[rnd][r3], W[m + 1], o_[px]));
                    o_[px + 1] = fdot2(w01[rnd][r3], A[m], fdot2(w2z[rnd][r3], A[m + 1], o_[px + 1]));
                }
            }
            uint4 o4;
            o4.x = (unsigned)f2h(o_[0]) | ((unsigned)f2h(o_[1]) << 16);
            o4.y = (unsigned)f2h(o_[2]) | ((unsigned)f2h(o_[3]) << 16);
            o4.z = (unsigned)f2h(o_[4]) | ((unsigned)f2h(o_[5]) << 16);
            o4.w = (unsigned)f2h(o_[6]) | ((unsigned)f2h(o_[7]) << 16);
            int cb = (rnd & 1) * 64 + oc;
            int cs = cb & 7;
            if (rnd < 2) {
                // q -> region B, 64 u16/channel, slot-XOR layout
                *(uint4*)(su + Q_U + cb * 64 + ((py ^ cs) * 8)) = o4;
            } else if (rnd < 4) {
                // k -> paired layout: kp[m] = (k[m], k[(m-1)&7]) per row, so
                // stage 3 needs zero prep. 2 x b128 per row, row-XOR spreads banks.
                unsigned kw[4] = {o4.x, o4.y, o4.z, o4.w};
                uint4 p0, p1;
                p0.x = __builtin_amdgcn_perm(kw[3], kw[0], 0x07060100u);
                p0.y = __builtin_amdgcn_alignbit(kw[0], kw[0], 16);
                p0.z = __builtin_amdgcn_perm(kw[0], kw[1], 0x07060100u);
                p0.w = __builtin_amdgcn_alignbit(kw[1], kw[1], 16);
                p1.x = __builtin_amdgcn_perm(kw[1], kw[2], 0x07060100u);
                p1.y = __builtin_amdgcn_alignbit(kw[2], kw[2], 16);
                p1.z = __builtin_amdgcn_perm(kw[2], kw[3], 0x07060100u);
                p1.w = __builtin_amdgcn_alignbit(kw[3], kw[3], 16);
                unsigned short* kd = su + KP_U + cb * 128 + ((py ^ cs) * 16);
                *(uint4*)kd = p0;
                *(uint4*)(kd + 8) = p1;
            } else if (rnd == 4) {
                vA = o4;                     // v channel oc
            } else {
                vB = o4;                     // v channel 64+oc
            }
        }
        if (rnd < 5) {
#pragma unroll
            for (int ks = 0; ks < 4; ++ks) wa[ks] = wn[ks];
        }
    }
    // NOTE: post-loop barrier removed. Proof: stage-3 writes CORR (region A =
    // HIDA). The last HIDA readers are rnd-4's dw loads, and every thread's
    // rnd-4 dw precedes its arrival at the rnd-5 barrier (bar5). Any thread
    // executing stage-3 code is past bar5, hence ALL threads finished their
    // HIDA reads. Q/KP writes were fenced by the rnd-2..5 barriers. dw5 reads
    // HIDB (region D), untouched by stage 3 -> dw5 and stage 3 legally fuse
    // into one barrier-free region.

    // ---- 3) 8x8 circular conv via v_dot2_f32_f16; thread (oc,py): row py of
    //         channels oc and 64+oc. K pre-paired -> zero in-loop prep. ----
    {
        int oc = dw_oc, py = dw_py;
#pragma unroll
        for (int cc = 0; cc < 2; ++cc) {
            int c = oc + cc * 64, cs = c & 7;
            const unsigned short* qr = su + Q_U  + c * 64;
            const unsigned short* kr = su + KP_U + c * 128;
            float o0[8] = {0.f,0.f,0.f,0.f,0.f,0.f,0.f,0.f};
#pragma unroll
            for (int a = 0; a < 8; ++a) {
                uint4 uq = *(const uint4*)(qr + ((a ^ cs) * 8));
                int k0 = (py - a) & 7;
                const unsigned short* kpr = kr + ((k0 ^ cs) * 16);
                uint4 uk0 = *(const uint4*)(kpr);
                uint4 uk1 = *(const uint4*)(kpr + 8);
                unsigned qw[4] = {uq.x, uq.y, uq.z, uq.w};
                unsigned kp[8] = {uk0.x, uk0.y, uk0.z, uk0.w, uk1.x, uk1.y, uk1.z, uk1.w};
#pragma unroll
                for (int j = 0; j < 8; ++j) {
#pragma unroll
                    for (int p = 0; p < 4; ++p)
                        o0[j] = fdot2(qw[p], kp[(j - 2 * p) & 7], o0[j]);
                }
            }
            uint4 a4;
            a4.x = (unsigned)f2h(o0[0]) | ((unsigned)f2h(o0[1]) << 16);
            a4.y = (unsigned)f2h(o0[2]) | ((unsigned)f2h(o0[3]) << 16);
            a4.z = (unsigned)f2h(o0[4]) | ((unsigned)f2h(o0[5]) << 16);
            a4.w = (unsigned)f2h(o0[6]) | ((unsigned)f2h(o0[7]) << 16);
            *(uint4*)(su + CORRU + c * 64 + ((py ^ cs) * 8)) = a4;
        }
    }
    // Prefetch stage-6 hi A-fragments (global, L2-hot) before the barrier so
    // they land during stages 4-5 instead of stalling stage 6's MFMA chain.
    s16x8 pfh[8];
    if (wv < 4) {
        const s16x8* whi = (const s16x8*)(wsu + 24576);
#pragma unroll
        for (int ks = 0; ks < 8; ++ks)
            pfh[ks] = whi[(p6_mtp * 8 + ks) * 64 + ln];
    }
    __syncthreads();

    // ---- 4) LayerNorm stats: 8 partial groups x 64 px (RED aliases dead Q) ----
    {
        float* redF = (float*)(su + REDU);
        int px = tid & 63, grp = tid >> 6;     // grp 0..7
        int prow = px >> 3, pcol = px & 7;
        float s = 0.f, s2 = 0.f;
#pragma unroll
        for (int i = 0; i < 16; ++i) {
            int c = i * 8 + grp;
            float v = (float)__builtin_bit_cast(_Float16,
                        su[CORRU + c * 64 + ((prow ^ (c & 7)) * 8) + pcol]);
            s += v; s2 += v * v;
        }
        redF[grp * 64 + px] = s;
        redF[512 + grp * 64 + px] = s2;
    }
    __syncthreads();
    if (tid < 64) {
        float* redF = (float*)(su + REDU);
        float s = 0.f, s2 = 0.f;
#pragma unroll
        for (int g = 0; g < 8; ++g) {
            s  += redF[g * 64 + tid];
            s2 += redF[512 + g * 64 + tid];
        }
        float m = s * (1.f / 128.f);
        float var = s2 * (1.f / 128.f) - m * m;
        ((float*)(su + MU_U))[tid] = m;
        ((float*)(su + RS_U))[tid] = rsqrtf(var + 1e-5f);
    }
    __syncthreads();

    // ---- 5) normalize + affine + gate(V regs) -> bf16 B-frags (BFR aliases Q/RED) ----
    {
        int oc = dw_oc, py = dw_py;
        const float* muF = (const float*)(su + MU_U);
        const float* rsF = (const float*)(su + RS_U);
        float4 m0 = *(const float4*)(muF + py * 8);
        float4 m1 = *(const float4*)(muF + py * 8 + 4);
        float4 r0 = *(const float4*)(rsF + py * 8);
        float4 r1 = *(const float4*)(rsF + py * 8 + 4);
        float mm[8] = {m0.x, m0.y, m0.z, m0.w, m1.x, m1.y, m1.z, m1.w};
        float rr[8] = {r0.x, r0.y, r0.z, r0.w, r1.x, r1.y, r1.z, r1.w};
#pragma unroll
        for (int cc = 0; cc < 2; ++cc) {
            int c = oc + cc * 64, cs = c & 7;
            uint4 cu = *(const uint4*)(su + CORRU + c * 64 + ((py ^ cs) * 8));
            h16x8 ch = __builtin_bit_cast(h16x8, cu);
            h16x8 vh = __builtin_bit_cast(h16x8, cc ? vB : vA);
            float wc = lnw[c], bc = lnb[c];
            int base = BFRU + (((py >> 2) * 8 + (c >> 4)) * 64 + 8 * (py & 3) + 32 * ((c >> 3) & 1)) * 8 + (c & 7);
#pragma unroll
            for (int j = 0; j < 8; ++j) {
                float t = (((float)ch[j] - mm[j]) * rr[j] * wc + bc) * (float)vh[j];
                su[base + j * 8] = f2bf(t);
            }
        }
    }
    __syncthreads();

    // ---- 6) projection 128 -> 64: 4 waves, full-K, single accumulator
    //         (hi frags prefetched; lo loaded inline), direct f32 store ----
    if (wv < 4) {
        int mtp = p6_mtp, ntp = p6_ntp;
        const s16x8* wlo = (const s16x8*)(wsu + 32768);
        f32x16 acc = {};
#pragma unroll
        for (int ks = 0; ks < 8; ++ks) {
            s16x8 bfr = *(const s16x8*)(su + BFRU + ((ntp * 8 + ks) * 64 + ln) * 8);
            acc = __builtin_amdgcn_mfma_f32_32x32x16_bf16(pfh[ks], bfr, acc, 0, 0, 0);
            s16x8 al  = wlo[(mtp * 8 + ks) * 64 + ln];
            acc = __builtin_amdgcn_mfma_f32_32x32x16_bf16(al, bfr, acc, 0, 0, 0);
        }
        int px = ntp * 32 + l32;
        int py = px >> 3, wx = px & 7;
#pragma unroll
        for (int r = 0; r < 16; ++r) {
            int row = (r >> 2) * 8 + half * 4 + (r & 3);
            int o = mtp * 32 + row;
            out[(((size_t)(b * 64 + o) * HH) + h0 + py) * WW + w0 + wx] = acc[r];
        }
    }
}

extern "C" void kernel_launch(void* const* d_in, const int* in_sizes, int n_in,
                              void* d_out, int out_size, void* d_ws, size_t ws_size,
                              hipStream_t stream) {
    const float* x    = (const float*)d_in[0];
    const float* w1   = (const float*)d_in[1];
    const float* wdw  = (const float*)d_in[2];
    const float* wout = (const float*)d_in[3];
    const float* lnw  = (const float*)d_in[4];
    const float* lnb  = (const float*)d_in[5];
    float* o = (float*)d_out;
    unsigned short* ws = (unsigned short*)d_ws;

    fsas_prepack<<<160, 256, 0, stream>>>(w1, wout, ws);
    dim3 grid(32, 32, NB);
    fsas_fused<<<grid, dim3(NTHREADS), 0, stream>>>(x, wdw, ws, lnw, lnb, o);
}